// Round 1
// 280.095 us; speedup vs baseline: 1.0191x; 1.0191x over previous
//
#include <hip/hip_runtime.h>
#include <hip/hip_bf16.h>
#include <stdint.h>

// QuantizedCpuLinear: y = scale * (x @ wq^T)
// x: f32 [8192,4096]; wq int8-valued delivered as int32 [4096,4096] (K contig);
// out f32 [8192,4096]. bf16 MFMA GEMM, 256x256 tile, BK=64, 8 waves.
// This version: m201-style 4-sub-phase schedule per K-tile with raw s_barrier,
// counted vmcnt(4) (T3+T4), global_load_lds with inverse-swizzled global source
// (rule 21), XOR-swizzled LDS reads (T2), setprio around MFMA (T5), XCD swz (T1).

#define M_DIM 8192
#define N_DIM 4096
#define K_DIM 4096
#define BM 256
#define BN 256
#define BK 64
#define NT (K_DIM / BK)          // 64

typedef __attribute__((ext_vector_type(4))) float    f32x4;
typedef __attribute__((ext_vector_type(4))) int      i32x4;
typedef __attribute__((ext_vector_type(2))) uint32_t u32x2;
typedef __attribute__((ext_vector_type(4))) uint32_t u32x4;
typedef __attribute__((ext_vector_type(8))) short    bf16x8;
typedef uint32_t u32;

__device__ __forceinline__ u32 fbits(float f) { return __builtin_bit_cast(u32, f); }
// two f32 -> two bf16 by truncation (1 v_perm_b32); exact for int8-valued floats.
__device__ __forceinline__ u32 pack_bf16_trunc(float lo, float hi) {
    return __builtin_amdgcn_perm(fbits(hi), fbits(lo), 0x07060302u);
}
// LDS byte address for logical (row, byte-col) in a [256][128B] tile (old kernel).
__device__ __forceinline__ int swzb(int row, int bytecol) {
    return row * 128 + (bytecol ^ ((row & 7) << 4));
}

// global_load_lds, 16B per lane. LDS dst must be wave-uniform; HW writes
// dst + lane*16. Pointers cast via integers (low 32 bits of a generic LDS
// pointer are the LDS offset on gfx9+).
__device__ __forceinline__ void gload_lds16(const void* g, void* s) {
    __builtin_amdgcn_global_load_lds(
        (const __attribute__((address_space(1))) void*)(uintptr_t)g,
        (__attribute__((address_space(3))) void*)(u32)(uintptr_t)s, 16, 0, 0);
}

#define WAIT_LGKM0() do { asm volatile("s_waitcnt lgkmcnt(0)" ::: "memory"); \
                          __builtin_amdgcn_sched_barrier(0); } while (0)
#define WAIT_VM4()   do { asm volatile("s_waitcnt vmcnt(4)" ::: "memory");   \
                          __builtin_amdgcn_sched_barrier(0); } while (0)
#define WAIT_VM0()   do { asm volatile("s_waitcnt vmcnt(0)" ::: "memory");   \
                          __builtin_amdgcn_sched_barrier(0); } while (0)
#define BARRIER()    __builtin_amdgcn_s_barrier()

// ---- pre-convert: W int32 -> bf16 (same layout) ----
__global__ __launch_bounds__(256)
void qlin_convert_w(const int* __restrict__ Wq, short* __restrict__ Wb)
{
    const size_t i = (size_t)blockIdx.x * 256 + threadIdx.x;   // 8 elts/thread
    i32x4 w0 = ((const i32x4*)Wq)[2 * i];
    i32x4 w1 = ((const i32x4*)Wq)[2 * i + 1];
    u32x4 q;
    q[0] = pack_bf16_trunc((float)w0[0], (float)w0[1]);
    q[1] = pack_bf16_trunc((float)w0[2], (float)w0[3]);
    q[2] = pack_bf16_trunc((float)w1[0], (float)w1[1]);
    q[3] = pack_bf16_trunc((float)w1[2], (float)w1[3]);
    ((u32x4*)Wb)[i] = q;
}

// ---- pre-convert: X f32 -> bf16 ----
__global__ __launch_bounds__(256)
void qlin_convert_x(const float* __restrict__ X, short* __restrict__ Xb)
{
    const size_t i = (size_t)blockIdx.x * 256 + threadIdx.x;   // 8 elts/thread
    f32x4 a = ((const f32x4*)X)[2 * i];
    f32x4 b = ((const f32x4*)X)[2 * i + 1];
    u32x4 q;
    q[0] = pack_bf16_trunc(a[0], a[1]);
    q[1] = pack_bf16_trunc(a[2], a[3]);
    q[2] = pack_bf16_trunc(b[0], b[1]);
    q[3] = pack_bf16_trunc(b[2], b[3]);
    ((u32x4*)Xb)[i] = q;
}

// ===================== main pipelined GEMM (bf16 inputs) =====================
// LDS per operand: [2 dbuf][2 half][128 rows][128 B]; half h = tile rows h*128..
// Logical (row128, bytecol) lives at physical byte row128*128 + (bytecol ^
// ((row128&7)<<4)). global_load_lds writes linearly, so the global source
// column is pre-swizzled with the same XOR (involution).
__global__ __launch_bounds__(512, 2)
void qlin_gemm_p(const short* __restrict__ A, const short* __restrict__ B,
                 const float* __restrict__ scale_p, float* __restrict__ C)
{
    __shared__ __align__(16) char As[2][2][128 * 128];   // 64 KiB
    __shared__ __align__(16) char Bs[2][2][128 * 128];   // 64 KiB

    const int tid = threadIdx.x;
    // XCD swizzle: nwg = 512, divisible by 8 -> bijective
    const int nwg = (M_DIM / BM) * (N_DIM / BN);   // 512
    const int cpx = nwg / 8;
    const int bid = ((int)blockIdx.x % 8) * cpx + (int)blockIdx.x / 8;
    const int tileM = (bid / (N_DIM / BN)) * BM;
    const int tileN = (bid % (N_DIM / BN)) * BN;

    const int lane = tid & 63;
    const int wid  = tid >> 6;       // 0..7
    const int wr   = wid >> 2;       // 0..1  (wave covers 128 M-rows = A half wr)
    const int wc   = wid & 3;        // 0..3  (wave covers 64 N-cols)
    const int lr   = lane & 15;
    const int lq   = lane >> 4;

    // staging source addressing (per lane): 8 rows x 128B per wave-issue
    const int srow = lane >> 3;                    // 0..7
    const int scol = ((lane & 7) ^ srow) << 4;     // inverse-swizzled byte col
    const char* Ag = (const char*)A;
    const char* Bg = (const char*)B;

    // stage one half-tile (2 x global_load_lds per thread)
    auto stageA = [&](int buf, int h, int kt) {
#pragma unroll
        for (int j = 0; j < 2; ++j) {
            const int seg = wid * 2 + j;           // 0..15
            const char* src = Ag + (size_t)(tileM + h * 128 + seg * 8 + srow) * (K_DIM * 2)
                                 + kt * (BK * 2) + scol;
            gload_lds16(src, &As[buf][h][seg * 1024]);
        }
    };
    auto stageB = [&](int buf, int h, int kt) {
#pragma unroll
        for (int j = 0; j < 2; ++j) {
            const int seg = wid * 2 + j;
            const char* src = Bg + (size_t)(tileN + h * 128 + seg * 8 + srow) * (K_DIM * 2)
                                 + kt * (BK * 2) + scol;
            gload_lds16(src, &Bs[buf][h][seg * 1024]);
        }
    };

    // ---- fragments ----
    f32x4  acc[8][4] = {};
    bf16x8 afr[4][2], b0fr[2][2], b2fr[2][2];

    auto swzh = [](int row, int bc) { return row * 128 + (bc ^ ((row & 7) << 4)); };
    auto ldA = [&](int buf, int mb) {
#pragma unroll
        for (int m = 0; m < 4; ++m) {
            const int row = (mb + m) * 16 + lr;                 // 0..127 in half wr
#pragma unroll
            for (int ks = 0; ks < 2; ++ks)
                afr[m][ks] = *(const bf16x8*)&As[buf][wr][swzh(row, ks * 64 + lq * 16)];
        }
    };
    auto ldB = [&](int buf, int nb, bf16x8 (&bf)[2][2]) {
#pragma unroll
        for (int n = 0; n < 2; ++n) {
            const int r = wc * 64 + (nb + n) * 16 + lr;         // 0..255
#pragma unroll
            for (int ks = 0; ks < 2; ++ks)
                bf[n][ks] = *(const bf16x8*)&Bs[buf][r >> 7][swzh(r & 127, ks * 64 + lq * 16)];
        }
    };
    auto quad = [&](int mb, int nb, bf16x8 (&bf)[2][2]) {
        __builtin_amdgcn_s_setprio(1);
#pragma unroll
        for (int m = 0; m < 4; ++m)
#pragma unroll
            for (int n = 0; n < 2; ++n)
#pragma unroll
                for (int ks = 0; ks < 2; ++ks)
                    acc[mb + m][nb + n] = __builtin_amdgcn_mfma_f32_16x16x32_bf16(
                        afr[m][ks], bf[n][ks], acc[mb + m][nb + n], 0, 0, 0);
        __builtin_amdgcn_s_setprio(0);
        __builtin_amdgcn_sched_barrier(0);
    };

    // ---- prologue: tile0 fully + tile1 B-halves; keep 4 loads in flight ----
    stageA(0, 0, 0); stageA(0, 1, 0);
    stageB(0, 0, 0); stageB(0, 1, 0);
    stageB(1, 0, 1); stageB(1, 1, 1);
    WAIT_VM4();          // tile0's 8 loads done; tile1's 4 B loads in flight
    BARRIER();

    // ---- main loop: 4 sub-phases per K-tile, 2 barriers/phase, counted vmcnt ----
    // Issue stream per thread: t.B0@P2(t-2), t.B1@P3(t-2), t.A0@P0(t-1), t.A1@P1(t-1).
    // Region-free proofs: buf[nxt].A last read P2(t-1) < P0(t) issue;
    // buf[cur].B half reads all retire by end-P1(t) barrier < P2/P3(t) issues.
#pragma unroll 1
    for (int kt = 0; kt < NT; ++kt) {
        const int cur = kt & 1, nxt = cur ^ 1;

        // P0: frags A(mb0), B(nb0); stage A-half0 of kt+1
        ldA(cur, 0); ldB(cur, 0, b0fr);
        if (kt + 1 < NT) stageA(nxt, 0, kt + 1);
        BARRIER(); WAIT_LGKM0();
        quad(0, 0, b0fr);
        BARRIER();

        // P1: frags B(nb2); stage A-half1 of kt+1
        ldB(cur, 2, b2fr);
        if (kt + 1 < NT) stageA(nxt, 1, kt + 1);
        BARRIER(); WAIT_LGKM0();
        quad(0, 2, b2fr);
        BARRIER();

        // P2: frags A(mb4); stage B-half0 of kt+2 (into cur, B fully read)
        ldA(cur, 4);
        if (kt + 2 < NT) stageB(cur, 0, kt + 2);
        BARRIER(); WAIT_LGKM0();
        quad(4, 2, b2fr);
        BARRIER();

        // P3: reuse b0fr; stage B-half1 of kt+2; counted wait for kt+1's tile
        if (kt + 2 < NT) stageB(cur, 1, kt + 2);
        BARRIER(); WAIT_LGKM0();
        quad(4, 0, b0fr);
        if (kt + 2 < NT)      { WAIT_VM4(); }   // kt+1 landed; kt+2 B in flight
        else if (kt + 1 < NT) { WAIT_VM0(); }   // tail: drain last tile's A
        BARRIER();
    }

    // ---- epilogue: C/D layout col=lane&15, row=(lane>>4)*4+reg ----
    const float scl = scale_p[0];
#pragma unroll
    for (int m = 0; m < 8; ++m) {
        const int gm0 = tileM + wr * 128 + m * 16 + lq * 4;
#pragma unroll
        for (int n = 0; n < 4; ++n) {
            const int gn = tileN + wc * 64 + n * 16 + lr;
            float* cp = C + (size_t)gm0 * N_DIM + gn;
#pragma unroll
            for (int r = 0; r < 4; ++r)
                cp[(size_t)r * N_DIM] = acc[m][n][r] * scl;
        }
    }
}

// ===================== fallback (no workspace): old reg-staged kernel ========
#define TILE_BYTES (BM * BK * 2)
template <int MODE>
__global__ __launch_bounds__(512, 2)
void qlin_gemm8(const void* __restrict__ Asrc, const void* __restrict__ Bsrc,
                const float* __restrict__ scale_p, float* __restrict__ C)
{
    __shared__ char As[2 * TILE_BYTES];
    __shared__ char Bs[2 * TILE_BYTES];

    const int tid = threadIdx.x;
    const int nwg = (M_DIM / BM) * (N_DIM / BN);
    const int cpx = nwg / 8;
    const int bid = ((int)blockIdx.x % 8) * cpx + (int)blockIdx.x / 8;
    const int tileM = (bid / (N_DIM / BN)) * BM;
    const int tileN = (bid % (N_DIM / BN)) * BN;

    const int lane = tid & 63;
    const int wid  = tid >> 6;
    const int wr   = wid >> 2;
    const int wc   = wid & 3;
    const int lr   = lane & 15;
    const int lq   = lane >> 4;

    f32x4  aF[8]; i32x4 wF[8];

    const float* ag0 = (const float*)Asrc + (size_t)(tileM + (tid >> 4)) * K_DIM + (tid & 15) * 4;
    const int*   bg0 = (const int*)Bsrc  + (size_t)(tileN + (tid >> 4)) * K_DIM + (tid & 15) * 4;

    auto stage_load = [&](int kt) {
#pragma unroll
        for (int i = 0; i < 8; ++i)
            aF[i] = *(const f32x4*)(ag0 + (size_t)(32 * i) * K_DIM + kt * BK);
#pragma unroll
        for (int i = 0; i < 8; ++i)
            wF[i] = *(const i32x4*)(bg0 + (size_t)(32 * i) * K_DIM + kt * BK);
    };
    auto stage_writeA = [&](int nxt) {
        char* dst = As + nxt * TILE_BYTES;
#pragma unroll
        for (int i = 0; i < 8; ++i) {
            u32x2 p;
            p[0] = pack_bf16_trunc(aF[i][0], aF[i][1]);
            p[1] = pack_bf16_trunc(aF[i][2], aF[i][3]);
            *(u32x2*)(dst + swzb((tid >> 4) + 32 * i, (tid & 15) * 8)) = p;
        }
    };
    auto stage_writeB = [&](int nxt) {
        char* dst = Bs + nxt * TILE_BYTES;
#pragma unroll
        for (int i = 0; i < 8; ++i) {
            u32x2 p;
            p[0] = pack_bf16_trunc((float)wF[i][0], (float)wF[i][1]);
            p[1] = pack_bf16_trunc((float)wF[i][2], (float)wF[i][3]);
            *(u32x2*)(dst + swzb((tid >> 4) + 32 * i, (tid & 15) * 8)) = p;
        }
    };

    f32x4  acc[8][4] = {};
    bf16x8 afr[4][2], bfr[2][2];

    auto ldA = [&](const char* buf, int mb) {
#pragma unroll
        for (int m = 0; m < 4; ++m) {
            const int row = wr * 128 + (mb + m) * 16 + lr;
#pragma unroll
            for (int ks = 0; ks < 2; ++ks)
                afr[m][ks] = *(const bf16x8*)(buf + swzb(row, ks * 64 + lq * 16));
        }
    };
    auto ldB = [&](const char* buf, int nb) {
#pragma unroll
        for (int n = 0; n < 2; ++n) {
            const int row = wc * 64 + (nb + n) * 16 + lr;
#pragma unroll
            for (int ks = 0; ks < 2; ++ks)
                bfr[n][ks] = *(const bf16x8*)(buf + swzb(row, ks * 64 + lq * 16));
        }
    };
    auto quad = [&](int mb, int nb) {
        __builtin_amdgcn_s_setprio(1);
#pragma unroll
        for (int m = 0; m < 4; ++m)
#pragma unroll
            for (int n = 0; n < 2; ++n)
#pragma unroll
                for (int ks = 0; ks < 2; ++ks)
                    acc[mb + m][nb + n] = __builtin_amdgcn_mfma_f32_16x16x32_bf16(
                        afr[m][ks], bfr[n][ks], acc[mb + m][nb + n], 0, 0, 0);
        __builtin_amdgcn_s_setprio(0);
    };

    stage_load(0);
    stage_writeA(0);
    stage_writeB(0);
    __syncthreads();

#pragma unroll 1
    for (int kt = 0; kt < NT; ++kt) {
        const int cur = kt & 1, nxt = cur ^ 1;
        const bool more = (kt + 1) < NT;
        const char* Ab = As + cur * TILE_BYTES;
        const char* Bb = Bs + cur * TILE_BYTES;

        if (more) stage_load(kt + 1);

        ldA(Ab, 0); ldB(Bb, 0); quad(0, 0);
        ldB(Bb, 2);             quad(0, 2);
        ldA(Ab, 4);
        if (more) stage_writeA(nxt);
        quad(4, 2);
        ldB(Bb, 0);
        if (more) stage_writeB(nxt);
        quad(4, 0);

        __syncthreads();
    }

    const float scl = scale_p[0];
#pragma unroll
    for (int m = 0; m < 8; ++m) {
        const int gm0 = tileM + wr * 128 + m * 16 + lq * 4;
#pragma unroll
        for (int n = 0; n < 4; ++n) {
            const int gn = tileN + wc * 64 + n * 16 + lr;
            float* cp = C + (size_t)gm0 * N_DIM + gn;
#pragma unroll
            for (int r = 0; r < 4; ++r)
                cp[(size_t)r * N_DIM] = acc[m][n][r] * scl;
        }
    }
}

extern "C" void kernel_launch(void* const* d_in, const int* in_sizes, int n_in,
                              void* d_out, int out_size, void* d_ws, size_t ws_size,
                              hipStream_t stream)
{
    (void)in_sizes; (void)n_in; (void)out_size;
    const float* X     = (const float*)d_in[0];
    const int*   Wq    = (const int*)d_in[1];      // int8-valued, delivered as int32
    const float* scale = (const float*)d_in[2];
    float* C = (float*)d_out;

    const dim3 gblock(256);
    const dim3 ggrid((M_DIM / BM) * (N_DIM / BN));  // 512
    const size_t xbytes = (size_t)M_DIM * K_DIM * sizeof(short);   // 64 MiB
    const size_t wbytes = (size_t)N_DIM * K_DIM * sizeof(short);   // 32 MiB

    if (ws_size >= xbytes + wbytes) {
        short* Xb = (short*)d_ws;
        short* Wb = (short*)((char*)d_ws + xbytes);
        qlin_convert_x<<<dim3((size_t)M_DIM * K_DIM / (8 * 256)), gblock, 0, stream>>>(X, Xb);
        qlin_convert_w<<<dim3((size_t)N_DIM * K_DIM / (8 * 256)), gblock, 0, stream>>>(Wq, Wb);
        qlin_gemm_p<<<ggrid, dim3(512), 0, stream>>>(Xb, Wb, scale, C);
    } else {
        qlin_gemm8<0><<<ggrid, dim3(512), 0, stream>>>(X, Wq, scale, C);
    }
}

// Round 2
// 268.786 us; speedup vs baseline: 1.0620x; 1.0421x over previous
//
#include <hip/hip_runtime.h>
#include <hip/hip_bf16.h>
#include <stdint.h>

// QuantizedCpuLinear: y = scale * (x @ wq^T)
// x: f32 [8192,4096]; wq int8-valued delivered as int32 [4096,4096] (K contig);
// out f32 [8192,4096]. bf16 MFMA GEMM, 256x256 tile, BK=64, 8 waves.
// R2: 2-barrier-per-K-tile schedule. All 24 ds_reads + A(t+1) stage issued up
// front; 32-MFMA cluster (compiler lgkm waits overlap read latency with MFMA);
// S1 barrier guards B re-stage; 32-MFMA cluster; vmcnt(4); S2 barrier.
// Swizzled LDS (T2), counted vmcnt (T4), setprio (T5), XCD swz (T1).

#define M_DIM 8192
#define N_DIM 4096
#define K_DIM 4096
#define BM 256
#define BN 256
#define BK 64
#define NT (K_DIM / BK)          // 64

typedef __attribute__((ext_vector_type(4))) float    f32x4;
typedef __attribute__((ext_vector_type(4))) int      i32x4;
typedef __attribute__((ext_vector_type(2))) uint32_t u32x2;
typedef __attribute__((ext_vector_type(4))) uint32_t u32x4;
typedef __attribute__((ext_vector_type(8))) short    bf16x8;
typedef uint32_t u32;

__device__ __forceinline__ u32 fbits(float f) { return __builtin_bit_cast(u32, f); }
// two f32 -> two bf16 by truncation (1 v_perm_b32); exact for int8-valued floats.
__device__ __forceinline__ u32 pack_bf16_trunc(float lo, float hi) {
    return __builtin_amdgcn_perm(fbits(hi), fbits(lo), 0x07060302u);
}
// LDS byte address for logical (row, byte-col) in a [256][128B] tile (fallback).
__device__ __forceinline__ int swzb(int row, int bytecol) {
    return row * 128 + (bytecol ^ ((row & 7) << 4));
}

// global_load_lds, 16B per lane. LDS dst is wave-uniform; HW writes dst+lane*16.
__device__ __forceinline__ void gload_lds16(const void* g, void* s) {
    __builtin_amdgcn_global_load_lds(
        (const __attribute__((address_space(1))) void*)(uintptr_t)g,
        (__attribute__((address_space(3))) void*)(u32)(uintptr_t)s, 16, 0, 0);
}

#define WAIT_VM4()   do { asm volatile("s_waitcnt vmcnt(4)" ::: "memory");   \
                          __builtin_amdgcn_sched_barrier(0); } while (0)
#define WAIT_VM0()   do { asm volatile("s_waitcnt vmcnt(0)" ::: "memory");   \
                          __builtin_amdgcn_sched_barrier(0); } while (0)
#define BARRIER()    do { __builtin_amdgcn_s_barrier();                      \
                          __builtin_amdgcn_sched_barrier(0); } while (0)

// ---- pre-convert: W int32 -> bf16 (same layout) ----
__global__ __launch_bounds__(256)
void qlin_convert_w(const int* __restrict__ Wq, short* __restrict__ Wb)
{
    const size_t i = (size_t)blockIdx.x * 256 + threadIdx.x;   // 8 elts/thread
    i32x4 w0 = ((const i32x4*)Wq)[2 * i];
    i32x4 w1 = ((const i32x4*)Wq)[2 * i + 1];
    u32x4 q;
    q[0] = pack_bf16_trunc((float)w0[0], (float)w0[1]);
    q[1] = pack_bf16_trunc((float)w0[2], (float)w0[3]);
    q[2] = pack_bf16_trunc((float)w1[0], (float)w1[1]);
    q[3] = pack_bf16_trunc((float)w1[2], (float)w1[3]);
    ((u32x4*)Wb)[i] = q;
}

// ---- pre-convert: X f32 -> bf16 ----
__global__ __launch_bounds__(256)
void qlin_convert_x(const float* __restrict__ X, short* __restrict__ Xb)
{
    const size_t i = (size_t)blockIdx.x * 256 + threadIdx.x;   // 8 elts/thread
    f32x4 a = ((const f32x4*)X)[2 * i];
    f32x4 b = ((const f32x4*)X)[2 * i + 1];
    u32x4 q;
    q[0] = pack_bf16_trunc(a[0], a[1]);
    q[1] = pack_bf16_trunc(a[2], a[3]);
    q[2] = pack_bf16_trunc(b[0], b[1]);
    q[3] = pack_bf16_trunc(b[2], b[3]);
    ((u32x4*)Xb)[i] = q;
}

// ===================== main pipelined GEMM (bf16 inputs) =====================
// LDS per operand: [2 dbuf][2 half][128 rows][128 B]. Logical (row,bytecol) at
// physical row*128 + (bytecol ^ ((row&7)<<4)); global source pre-swizzled with
// the same XOR so global_load_lds's linear write lands swizzled (rule 21).
__global__ __launch_bounds__(512, 2)
void qlin_gemm_p(const short* __restrict__ A, const short* __restrict__ B,
                 const float* __restrict__ scale_p, float* __restrict__ C)
{
    __shared__ __align__(16) char As[2][2][128 * 128];   // 64 KiB
    __shared__ __align__(16) char Bs[2][2][128 * 128];   // 64 KiB

    const int tid = threadIdx.x;
    // XCD swizzle: nwg = 512, divisible by 8 -> bijective
    const int nwg = (M_DIM / BM) * (N_DIM / BN);   // 512
    const int cpx = nwg / 8;
    const int bid = ((int)blockIdx.x % 8) * cpx + (int)blockIdx.x / 8;
    const int tileM = (bid / (N_DIM / BN)) * BM;
    const int tileN = (bid % (N_DIM / BN)) * BN;

    const int lane = tid & 63;
    const int wid  = tid >> 6;       // 0..7
    const int wr   = wid >> 2;       // 0..1  (wave covers 128 M-rows = A half wr)
    const int wc   = wid & 3;        // 0..3  (wave covers 64 N-cols)
    const int lr   = lane & 15;
    const int lq   = lane >> 4;

    // staging source addressing (per lane): 8 rows x 128B per wave-issue
    const int srow = lane >> 3;                    // 0..7
    const int scol = ((lane & 7) ^ srow) << 4;     // inverse-swizzled byte col
    const char* Ag = (const char*)A;
    const char* Bg = (const char*)B;

    // stage one half-tile (2 x global_load_lds per thread)
    auto stageA = [&](int buf, int h, int kt) {
#pragma unroll
        for (int j = 0; j < 2; ++j) {
            const int seg = wid * 2 + j;           // 0..15
            const char* src = Ag + (size_t)(tileM + h * 128 + seg * 8 + srow) * (K_DIM * 2)
                                 + kt * (BK * 2) + scol;
            gload_lds16(src, &As[buf][h][seg * 1024]);
        }
    };
    auto stageB = [&](int buf, int h, int kt) {
#pragma unroll
        for (int j = 0; j < 2; ++j) {
            const int seg = wid * 2 + j;
            const char* src = Bg + (size_t)(tileN + h * 128 + seg * 8 + srow) * (K_DIM * 2)
                                 + kt * (BK * 2) + scol;
            gload_lds16(src, &Bs[buf][h][seg * 1024]);
        }
    };

    // ---- fragments ----
    f32x4  acc[8][4] = {};
    bf16x8 afr[4][2];                // reused for mb0-3 then mb4-7 (reg economy)
    bf16x8 b0fr[2][2], b2fr[2][2];

    auto swzh = [](int row, int bc) { return row * 128 + (bc ^ ((row & 7) << 4)); };
    auto ldA = [&](int buf, int mb) {
#pragma unroll
        for (int m = 0; m < 4; ++m) {
            const int row = (mb + m) * 16 + lr;                 // 0..127 in half wr
#pragma unroll
            for (int ks = 0; ks < 2; ++ks)
                afr[m][ks] = *(const bf16x8*)&As[buf][wr][swzh(row, ks * 64 + lq * 16)];
        }
    };
    auto ldB = [&](int buf, int nb, bf16x8 (&bf)[2][2]) {
#pragma unroll
        for (int n = 0; n < 2; ++n) {
            const int r = wc * 64 + (nb + n) * 16 + lr;         // 0..255
#pragma unroll
            for (int ks = 0; ks < 2; ++ks)
                bf[n][ks] = *(const bf16x8*)&Bs[buf][r >> 7][swzh(r & 127, ks * 64 + lq * 16)];
        }
    };
    auto quad = [&](int mb, int nb, bf16x8 (&bf)[2][2]) {
#pragma unroll
        for (int m = 0; m < 4; ++m)
#pragma unroll
            for (int n = 0; n < 2; ++n)
#pragma unroll
                for (int ks = 0; ks < 2; ++ks)
                    acc[mb + m][nb + n] = __builtin_amdgcn_mfma_f32_16x16x32_bf16(
                        afr[m][ks], bf[n][ks], acc[mb + m][nb + n], 0, 0, 0);
    };

    // ---- prologue: tile0 fully + tile1 B-halves; keep 4 loads in flight ----
    stageA(0, 0, 0); stageA(0, 1, 0);
    stageB(0, 0, 0); stageB(0, 1, 0);
    stageB(1, 0, 1); stageB(1, 1, 1);
    WAIT_VM4();          // tile0's 8 loads landed; tile1's 4 B loads in flight
    BARRIER();

    // ---- main loop: 2 barriers + 1 counted vmcnt per K-tile ----
    // Entry invariant at tile t (buf c=t&1): A(t),B(t) landed in buf c;
    // B(t+1) [4 loads] in flight toward buf c^1.
    // Issue stream: A(t+1) both halves at tile top; B(t+2) both halves after S1.
    // Hazard proofs:
    //   stageA(nxt,t+1): buf nxt A last read in tile t-1, consumed by MFMAs
    //     issued before S2(t-1) barrier < this issue.
    //   stageB(cur,t+2): buf cur B reads (this tile) consumed by cluster-1
    //     MFMAs issued before S1 barrier < this issue.
    //   S2 vmcnt(4): outstanding = B(t+1)[4] + A(t+1)[4] + B(t+2)[4] = 12;
    //     leaves B(t+2); drains A(t+1) (1-tile lead) and B(t+1) (1.5-tile lead).
#pragma unroll 1
    for (int kt = 0; kt < NT; ++kt) {
        const int cur = kt & 1, nxt = cur ^ 1;

        // reads of cur + prefetch A(t+1)
        ldA(cur, 0);
        ldB(cur, 0, b0fr);
        ldB(cur, 2, b2fr);
        if (kt + 1 < NT) { stageA(nxt, 0, kt + 1); stageA(nxt, 1, kt + 1); }

        __builtin_amdgcn_s_setprio(1);
        quad(0, 0, b0fr);            // MFMA starts as soon as first frags land
        quad(0, 2, b2fr);
        __builtin_amdgcn_s_setprio(0);

        ldA(cur, 4);                 // reuse afr for mb4-7; latency hides under S1

        BARRIER();                   // S1: all waves' cur.B reads consumed
        if (kt + 2 < NT) { stageB(cur, 0, kt + 2); stageB(cur, 1, kt + 2); }

        __builtin_amdgcn_s_setprio(1);
        quad(4, 2, b2fr);
        quad(4, 0, b0fr);
        __builtin_amdgcn_s_setprio(0);

        if (kt + 2 < NT)      { WAIT_VM4(); }   // t+1 landed; B(t+2) in flight
        else if (kt + 1 < NT) { WAIT_VM0(); }   // tail: drain last tile
        BARRIER();                   // S2: tile boundary
    }

    // ---- epilogue: C/D layout col=lane&15, row=(lane>>4)*4+reg ----
    const float scl = scale_p[0];
#pragma unroll
    for (int m = 0; m < 8; ++m) {
        const int gm0 = tileM + wr * 128 + m * 16 + lq * 4;
#pragma unroll
        for (int n = 0; n < 4; ++n) {
            const int gn = tileN + wc * 64 + n * 16 + lr;
            float* cp = C + (size_t)gm0 * N_DIM + gn;
#pragma unroll
            for (int r = 0; r < 4; ++r)
                cp[(size_t)r * N_DIM] = acc[m][n][r] * scl;
        }
    }
}

// ===================== fallback (no workspace): reg-staged kernel ============
#define TILE_BYTES (BM * BK * 2)
__global__ __launch_bounds__(512, 2)
void qlin_gemm8(const void* __restrict__ Asrc, const void* __restrict__ Bsrc,
                const float* __restrict__ scale_p, float* __restrict__ C)
{
    __shared__ char As[2 * TILE_BYTES];
    __shared__ char Bs[2 * TILE_BYTES];

    const int tid = threadIdx.x;
    const int nwg = (M_DIM / BM) * (N_DIM / BN);
    const int cpx = nwg / 8;
    const int bid = ((int)blockIdx.x % 8) * cpx + (int)blockIdx.x / 8;
    const int tileM = (bid / (N_DIM / BN)) * BM;
    const int tileN = (bid % (N_DIM / BN)) * BN;

    const int lane = tid & 63;
    const int wid  = tid >> 6;
    const int wr   = wid >> 2;
    const int wc   = wid & 3;
    const int lr   = lane & 15;
    const int lq   = lane >> 4;

    f32x4  aF[8]; i32x4 wF[8];

    const float* ag0 = (const float*)Asrc + (size_t)(tileM + (tid >> 4)) * K_DIM + (tid & 15) * 4;
    const int*   bg0 = (const int*)Bsrc  + (size_t)(tileN + (tid >> 4)) * K_DIM + (tid & 15) * 4;

    auto stage_load = [&](int kt) {
#pragma unroll
        for (int i = 0; i < 8; ++i)
            aF[i] = *(const f32x4*)(ag0 + (size_t)(32 * i) * K_DIM + kt * BK);
#pragma unroll
        for (int i = 0; i < 8; ++i)
            wF[i] = *(const i32x4*)(bg0 + (size_t)(32 * i) * K_DIM + kt * BK);
    };
    auto stage_writeA = [&](int nxt) {
        char* dst = As + nxt * TILE_BYTES;
#pragma unroll
        for (int i = 0; i < 8; ++i) {
            u32x2 p;
            p[0] = pack_bf16_trunc(aF[i][0], aF[i][1]);
            p[1] = pack_bf16_trunc(aF[i][2], aF[i][3]);
            *(u32x2*)(dst + swzb((tid >> 4) + 32 * i, (tid & 15) * 8)) = p;
        }
    };
    auto stage_writeB = [&](int nxt) {
        char* dst = Bs + nxt * TILE_BYTES;
#pragma unroll
        for (int i = 0; i < 8; ++i) {
            u32x2 p;
            p[0] = pack_bf16_trunc((float)wF[i][0], (float)wF[i][1]);
            p[1] = pack_bf16_trunc((float)wF[i][2], (float)wF[i][3]);
            *(u32x2*)(dst + swzb((tid >> 4) + 32 * i, (tid & 15) * 8)) = p;
        }
    };

    f32x4  acc[8][4] = {};
    bf16x8 afr[4][2], bfr[2][2];

    auto ldA = [&](const char* buf, int mb) {
#pragma unroll
        for (int m = 0; m < 4; ++m) {
            const int row = wr * 128 + (mb + m) * 16 + lr;
#pragma unroll
            for (int ks = 0; ks < 2; ++ks)
                afr[m][ks] = *(const bf16x8*)(buf + swzb(row, ks * 64 + lq * 16));
        }
    };
    auto ldB = [&](const char* buf, int nb) {
#pragma unroll
        for (int n = 0; n < 2; ++n) {
            const int row = wc * 64 + (nb + n) * 16 + lr;
#pragma unroll
            for (int ks = 0; ks < 2; ++ks)
                bfr[n][ks] = *(const bf16x8*)(buf + swzb(row, ks * 64 + lq * 16));
        }
    };
    auto quad = [&](int mb, int nb) {
        __builtin_amdgcn_s_setprio(1);
#pragma unroll
        for (int m = 0; m < 4; ++m)
#pragma unroll
            for (int n = 0; n < 2; ++n)
#pragma unroll
                for (int ks = 0; ks < 2; ++ks)
                    acc[mb + m][nb + n] = __builtin_amdgcn_mfma_f32_16x16x32_bf16(
                        afr[m][ks], bfr[n][ks], acc[mb + m][nb + n], 0, 0, 0);
        __builtin_amdgcn_s_setprio(0);
    };

    stage_load(0);
    stage_writeA(0);
    stage_writeB(0);
    __syncthreads();

#pragma unroll 1
    for (int kt = 0; kt < NT; ++kt) {
        const int cur = kt & 1, nxt = cur ^ 1;
        const bool more = (kt + 1) < NT;
        const char* Ab = As + cur * TILE_BYTES;
        const char* Bb = Bs + cur * TILE_BYTES;

        if (more) stage_load(kt + 1);

        ldA(Ab, 0); ldB(Bb, 0); quad(0, 0);
        ldB(Bb, 2);             quad(0, 2);
        ldA(Ab, 4);
        if (more) stage_writeA(nxt);
        quad(4, 2);
        ldB(Bb, 0);
        if (more) stage_writeB(nxt);
        quad(4, 0);

        __syncthreads();
    }

    const float scl = scale_p[0];
#pragma unroll
    for (int m = 0; m < 8; ++m) {
        const int gm0 = tileM + wr * 128 + m * 16 + lq * 4;
#pragma unroll
        for (int n = 0; n < 4; ++n) {
            const int gn = tileN + wc * 64 + n * 16 + lr;
            float* cp = C + (size_t)gm0 * N_DIM + gn;
#pragma unroll
            for (int r = 0; r < 4; ++r)
                cp[(size_t)r * N_DIM] = acc[m][n][r] * scl;
        }
    }
}

extern "C" void kernel_launch(void* const* d_in, const int* in_sizes, int n_in,
                              void* d_out, int out_size, void* d_ws, size_t ws_size,
                              hipStream_t stream)
{
    (void)in_sizes; (void)n_in; (void)out_size;
    const float* X     = (const float*)d_in[0];
    const int*   Wq    = (const int*)d_in[1];      // int8-valued, delivered as int32
    const float* scale = (const float*)d_in[2];
    float* C = (float*)d_out;

    const dim3 gblock(256);
    const dim3 ggrid((M_DIM / BM) * (N_DIM / BN));  // 512
    const size_t xbytes = (size_t)M_DIM * K_DIM * sizeof(short);   // 64 MiB
    const size_t wbytes = (size_t)N_DIM * K_DIM * sizeof(short);   // 32 MiB

    if (ws_size >= xbytes + wbytes) {
        short* Xb = (short*)d_ws;
        short* Wb = (short*)((char*)d_ws + xbytes);
        qlin_convert_x<<<dim3((size_t)M_DIM * K_DIM / (8 * 256)), gblock, 0, stream>>>(X, Xb);
        qlin_convert_w<<<dim3((size_t)N_DIM * K_DIM / (8 * 256)), gblock, 0, stream>>>(Wq, Wb);
        qlin_gemm_p<<<ggrid, dim3(512), 0, stream>>>(Xb, Wb, scale, C);
    } else {
        qlin_gemm8<<<ggrid, dim3(512), 0, stream>>>(X, Wq, scale, C);
    }
}